// Round 13
// baseline (236.463 us; speedup 1.0000x reference)
//
#include <hip/hip_runtime.h>
#include <hip/hip_bf16.h>
#include <math.h>

#define B_N 4096
#define M_N 128
#define F_N 32
#define H_N 512
#define NFM 4096   // F*M

// wave-local LDS sync: all lanes of a wave run in lockstep, so a waitcnt on
// outstanding LDS ops makes prior cross-lane LDS writes visible to reads.
#define WAVE_SYNC() do { \
  asm volatile("s_waitcnt lgkmcnt(0)" ::: "memory"); \
  __builtin_amdgcn_sched_barrier(0); \
} while (0)

// ---------------------------------------------------------------------------
// Kernel 1: occupied-index extraction (wave ballot) + hidden layer.
// No atomics: writes the 128-bit occupancy mask per sample; buckets built
// deterministically by k_fill (fused count+fill), sorted by ascending b.
//   h[b,:] = tanhf( sum_j W1[idx_j,:] + b1 )   (ascending-j chain, fp32)
// ---------------------------------------------------------------------------
__global__ __launch_bounds__(256) void k1_idx_h(
    const float* __restrict__ n, const float* __restrict__ W1,
    const float* __restrict__ b1, float* __restrict__ h_ws,
    unsigned int* __restrict__ mask)
{
  __shared__ int s_idx[F_N];
  __shared__ int s_cnt0;
  const int b = blockIdx.x;
  const int t = threadIdx.x;

  bool p = false;
  int before = 0;
  if (t < 128) {
    float v = n[(size_t)b * M_N + t];
    p = v > 0.5f;
    unsigned long long m = __ballot(p);
    int lane = t & 63;
    before = __popcll(m & ((1ull << lane) - 1ull));
    if (lane == 0) {
      if (t < 64) { mask[b*4+0] = (unsigned)m; mask[b*4+1] = (unsigned)(m>>32); }
      else        { mask[b*4+2] = (unsigned)m; mask[b*4+3] = (unsigned)(m>>32); }
    }
    if (t < 64) {
      if (lane == 0) s_cnt0 = __popcll(m);
      if (p) s_idx[before] = t;          // ascending within wave 0
    }
  }
  __syncthreads();
  if (t >= 64 && t < 128 && p) s_idx[s_cnt0 + before] = t;
  __syncthreads();

  #pragma unroll
  for (int cc = 0; cc < 2; ++cc) {
    int c = t + cc * 256;
    float acc = 0.0f;
    #pragma unroll
    for (int j = 0; j < F_N; ++j)
      acc += W1[(size_t)s_idx[j] * H_N + c];
    acc += b1[c];                        // b1 = zeros: exact
    h_ws[(size_t)b * H_N + c] = tanhf(acc);
  }
}

// ---------------------------------------------------------------------------
// k_w2t: pre-transpose W2 into bucket-friendly layout:
//   W2t[c*H_N*F_N + k*F_N + ig] = W2[k*NFM + ig*M_N + c]
// (round 9: killed the 128 MB in-k2 column-gather line amplification)
// ---------------------------------------------------------------------------
__global__ __launch_bounds__(256) void k_w2t(
    const float* __restrict__ W2, float* __restrict__ W2t)
{
  __shared__ float lds[32 * 132];
  const int k = blockIdx.x;
  const int t = threadIdx.x;

  #pragma unroll
  for (int i = 0; i < 4; ++i) {
    int m0 = i * 1024 + t * 4;             // never crosses a 128 boundary
    float4 v = *(const float4*)&W2[(size_t)k * NFM + m0];
    int ig = m0 >> 7, c = m0 & 127;
    lds[ig * 132 + c + 0] = v.x;
    lds[ig * 132 + c + 1] = v.y;
    lds[ig * 132 + c + 2] = v.z;
    lds[ig * 132 + c + 3] = v.w;
  }
  __syncthreads();

  const int c  = t >> 1;
  const int ih = (t & 1) * 16;
  float* outp = W2t + (size_t)c * (H_N * F_N) + k * F_N + ih;
  #pragma unroll
  for (int i = 0; i < 4; ++i) {
    int ig = ih + i * 4;
    float4 v = make_float4(lds[(ig + 0) * 132 + c], lds[(ig + 1) * 132 + c],
                           lds[(ig + 2) * 132 + c], lds[(ig + 3) * 132 + c]);
    *(float4*)(outp + i * 4) = v;
  }
}

// ---------------------------------------------------------------------------
// k_fill (fused count+fill):
// Pass 1: block c computes cnt_c AND boff_c = sum_b rank_b(c) directly.
// Pass 2: deterministic fill, entries sorted by ascending sample b:
//   bent[c*B_N + pos] = (b<<5) | j ;  loc[b*32 + j] = boff_c + pos
// ---------------------------------------------------------------------------
__global__ __launch_bounds__(256) void k_fill(
    const unsigned int* __restrict__ mask,
    int* __restrict__ bcnt, int* __restrict__ boff,
    int* __restrict__ bent, int* __restrict__ loc)
{
  const int c = blockIdx.x;
  const int t = threadIdx.x;
  const int w = t >> 6, lane = t & 63;
  const int word = c >> 5, bit = c & 31;
  __shared__ int s_wcnt[4];
  __shared__ int s_red[8];
  __shared__ int s_run;

  // ---- pass 1: count + offset ----
  int cnt_loc = 0, off_loc = 0;
  for (int b = t; b < B_N; b += 256) {
    unsigned m0 = mask[(size_t)b*4+0], m1 = mask[(size_t)b*4+1];
    unsigned m2 = mask[(size_t)b*4+2], m3 = mask[(size_t)b*4+3];
    unsigned wv = (word == 0) ? m0 : (word == 1) ? m1 : (word == 2) ? m2 : m3;
    cnt_loc += (int)((wv >> bit) & 1u);
    int r = __popc(wv & ((1u << bit) - 1u));
    if (word > 0) r += __popc(m0);
    if (word > 1) r += __popc(m1);
    if (word > 2) r += __popc(m2);
    off_loc += r;
  }
  #pragma unroll
  for (int off = 32; off > 0; off >>= 1) {
    cnt_loc += __shfl_down(cnt_loc, off);
    off_loc += __shfl_down(off_loc, off);
  }
  if (lane == 0) { s_red[w] = cnt_loc; s_red[4 + w] = off_loc; }
  __syncthreads();
  const int cnt_tot = s_red[0] + s_red[1] + s_red[2] + s_red[3];
  const int off_tot = s_red[4] + s_red[5] + s_red[6] + s_red[7];
  if (t == 0) { bcnt[c] = cnt_tot; boff[c] = off_tot; s_run = 0; }
  __syncthreads();

  // ---- pass 2: fill (ascending b) ----
  for (int chunk = 0; chunk < B_N; chunk += 256) {
    const int b = chunk + t;
    unsigned m0 = mask[(size_t)b*4+0], m1 = mask[(size_t)b*4+1];
    unsigned m2 = mask[(size_t)b*4+2], m3 = mask[(size_t)b*4+3];
    unsigned wv = (word == 0) ? m0 : (word == 1) ? m1 : (word == 2) ? m2 : m3;
    bool p = (wv >> bit) & 1u;
    int j = __popc(wv & ((1u << bit) - 1u));
    if (word > 0) j += __popc(m0);
    if (word > 1) j += __popc(m1);
    if (word > 2) j += __popc(m2);

    unsigned long long bal = __ballot(p);
    int before = __popcll(bal & ((1ull << lane) - 1ull));
    if (lane == 0) s_wcnt[w] = __popcll(bal);
    __syncthreads();
    int wbase = s_run;
    for (int i = 0; i < w; ++i) wbase += s_wcnt[i];
    if (p) {
      int pos = wbase + before;              // bucket-local, ascending b
      bent[(size_t)c * B_N + pos] = (b << 5) | j;
      loc[b * 32 + j] = off_tot + pos;
    }
    __syncthreads();
    if (t == 0) s_run += s_wcnt[0] + s_wcnt[1] + s_wcnt[2] + s_wcnt[3];
    __syncthreads();
  }
}

// ---------------------------------------------------------------------------
// Kernel 2 (ROUND 24): BUCKETED GEMM — LDS-FREE, BARRIER-FREE K-LOOP.
// Rounds 9/11/12 plateau diagnosis: time x VALUBusy = 37-39 us in ALL staged
//   configs — identical VALU work, differing only in stall fraction. The
//   stall is structural: a block-wide barrier drain per k-tile + the LDS
//   round-trip. So: remove LDS from the K-loop entirely.
// r9 thread-map (tyr=tid>>3 -> rows tyr*4..+3, tx=tid&7 -> cols tx*4..+3)
//   makes direct register loads wave-friendly:
//   - B: lanes' w2tc[k*32+tx*4] tile ONE contiguous 128 B row per wave-load
//     (perfect coalesce; 64 KB panel L2-resident).
//   - A: h[row][k..k+3] float4 = 8 distinct 16 B segments/wave-load, each
//     broadcast to 8 lanes; per-quad block working set 2 KB -> L1/L2 hits.
// K-loop = 128 k-quads (float4 along k), register double-buffered with
//   NAMED float4 sets (rule #20: all static indexing), 2 quads per
//   iteration. Zero barriers, zero LDS traffic after the one-time s_b load
//   -> waves drift freely, latency self-hiding; issue cap ~75-80% VALUBusy.
// ARITHMETIC BIT-IDENTICAL: quads ascending, components x->w ascending =
//   global k ascending; single accumulator; epilogue Phi + (acc + b2)
//   unchanged. absmax must stay exactly 0.203125.
// ---------------------------------------------------------------------------
#define QK(A0,A1,A2,A3,C,BV) do { \
  acc[0][0]=fmaf(A0.C,BV.x,acc[0][0]); acc[0][1]=fmaf(A0.C,BV.y,acc[0][1]); \
  acc[0][2]=fmaf(A0.C,BV.z,acc[0][2]); acc[0][3]=fmaf(A0.C,BV.w,acc[0][3]); \
  acc[1][0]=fmaf(A1.C,BV.x,acc[1][0]); acc[1][1]=fmaf(A1.C,BV.y,acc[1][1]); \
  acc[1][2]=fmaf(A1.C,BV.z,acc[1][2]); acc[1][3]=fmaf(A1.C,BV.w,acc[1][3]); \
  acc[2][0]=fmaf(A2.C,BV.x,acc[2][0]); acc[2][1]=fmaf(A2.C,BV.y,acc[2][1]); \
  acc[2][2]=fmaf(A2.C,BV.z,acc[2][2]); acc[2][3]=fmaf(A2.C,BV.w,acc[2][3]); \
  acc[3][0]=fmaf(A3.C,BV.x,acc[3][0]); acc[3][1]=fmaf(A3.C,BV.y,acc[3][1]); \
  acc[3][2]=fmaf(A3.C,BV.z,acc[3][2]); acc[3][3]=fmaf(A3.C,BV.w,acc[3][3]); \
} while(0)

#define QUAD(A0,A1,A2,A3,B0,B1,B2,B3) do { \
  QK(A0,A1,A2,A3,x,B0); QK(A0,A1,A2,A3,y,B1); \
  QK(A0,A1,A2,A3,z,B2); QK(A0,A1,A2,A3,w,B3); \
} while(0)

// KOFF in floats along k; B row k lives at bp + k*32
#define LDQ(AA0,AA1,AA2,AA3,BB0,BB1,BB2,BB3,KOFF) do { \
  AA0 = *(const float4*)(ap0 + (KOFF)); \
  AA1 = *(const float4*)(ap1 + (KOFF)); \
  AA2 = *(const float4*)(ap2 + (KOFF)); \
  AA3 = *(const float4*)(ap3 + (KOFF)); \
  BB0 = *(const float4*)(bp + (KOFF) * 32); \
  BB1 = *(const float4*)(bp + (KOFF) * 32 + 32); \
  BB2 = *(const float4*)(bp + (KOFF) * 32 + 64); \
  BB3 = *(const float4*)(bp + (KOFF) * 32 + 96); \
} while(0)

__global__ __launch_bounds__(256) void k2_gemm_gather(
    const float* __restrict__ h, const float* __restrict__ W2t,
    const float* __restrict__ b2, const float* __restrict__ Phi,
    const int* __restrict__ bcnt, const int* __restrict__ boff,
    const int* __restrict__ bent, float* __restrict__ phi_bucket)
{
  __shared__ int s_b[128];

  const int tid = threadIdx.x;               // 0..255
  const int c   = blockIdx.x;                // orbital 0..127
  const int cnt = bcnt[c];
  const int t0  = blockIdx.y * 128;          // row-tile base within bucket
  if (t0 >= cnt) return;                     // block-uniform early exit
  const int base = boff[c];
  const float* w2tc = W2t + (size_t)c * (H_N * F_N);

  if (tid < 128) {
    int ii = t0 + tid;
    int e  = bent[(size_t)c * B_N + (ii < cnt ? ii : cnt - 1)];  // cnt >= 1
    s_b[tid] = e >> 5;
  }
  __syncthreads();

  const int tx  = tid & 7;                   // col group: igs tx*4..+3
  const int tyr = tid >> 3;                  // row group 0..31: rows tyr*4..+3

  const float* ap0 = h + (size_t)s_b[tyr * 4 + 0] * H_N;
  const float* ap1 = h + (size_t)s_b[tyr * 4 + 1] * H_N;
  const float* ap2 = h + (size_t)s_b[tyr * 4 + 2] * H_N;
  const float* ap3 = h + (size_t)s_b[tyr * 4 + 3] * H_N;
  const float* bp  = w2tc + tx * 4;

  float acc[4][4];
  #pragma unroll
  for (int i = 0; i < 4; ++i)
    #pragma unroll
    for (int u = 0; u < 4; ++u) acc[i][u] = 0.f;

  float4 aA0, aA1, aA2, aA3, bA0, bA1, bA2, bA3;   // even-quad buffer
  float4 aB0, aB1, aB2, aB3, bB0, bB1, bB2, bB3;   // odd-quad buffer

  LDQ(aA0, aA1, aA2, aA3, bA0, bA1, bA2, bA3, 0);  // prologue: quad 0

  #pragma unroll 1
  for (int kq = 0; kq < 64; ++kq) {          // 2 quads (8 k) per iteration
    const int k0 = kq * 8;
    LDQ(aB0, aB1, aB2, aB3, bB0, bB1, bB2, bB3, k0 + 4);   // odd quad
    QUAD(aA0, aA1, aA2, aA3, bA0, bA1, bA2, bA3);          // k = k0..k0+3
    if (kq < 63)
      LDQ(aA0, aA1, aA2, aA3, bA0, bA1, bA2, bA3, k0 + 8); // next even quad
    QUAD(aB0, aB1, aB2, aB3, bB0, bB1, bB2, bB3);          // k = k0+4..k0+7
  }

  // ---- epilogue: coalesced float4 writes into bucket-major phi ----
  float ph[4], bb[4];
  #pragma unroll
  for (int u = 0; u < 4; ++u) {
    int colw = (tx * 4 + u) * M_N + c;
    ph[u] = Phi[colw];
    bb[u] = b2[colw];
  }
  #pragma unroll
  for (int i = 0; i < 4; ++i) {
    int r = tyr * 4 + i;
    if (t0 + r < cnt) {
      int col = base + t0 + r;               // global column index
      float v0 = ph[0] + (acc[i][0] + bb[0]);
      float v1 = ph[1] + (acc[i][1] + bb[1]);
      float v2 = ph[2] + (acc[i][2] + bb[2]);
      float v3 = ph[3] + (acc[i][3] + bb[3]);
      *(float4*)&phi_bucket[(size_t)col * 32 + tx * 4] =
          make_float4(v0, v1, v2, v3);
    }
  }
}

// ---------------------------------------------------------------------------
// Kernel 3: batched 32x32 fp32 LU replicating LAPACK sgetf2 exactly.
// Rank-1 update uses BOTH 32-lane halves (rows split [k+1,mid)/[mid,32);
// elements within an iteration are independent -> bit-identical).
// Loads columns from bucket-major phi_bucket via loc (contiguous 128 B).
// PLANAR complex output: out[0..B-1] = log|det|, out[B..2B-1] = arg(sign)
// ---------------------------------------------------------------------------
__global__ __launch_bounds__(256) void k3_det(
    const float* __restrict__ phi_bucket, const int* __restrict__ loc,
    float* __restrict__ out)
{
  __shared__ float A[4][32 * 33];
  const int w = threadIdx.x >> 6;
  const int lane = threadIdx.x & 63;
  const int b = blockIdx.x * 4 + w;
  float* Aw = A[w];

  {
    const int jj = lane & 31;
    const int hi = lane >> 5;              // 0 or 1: ig halves
    int lcol = loc[b * 32 + jj];
    const float* colp = phi_bucket + (size_t)lcol * 32 + hi * 16;
    #pragma unroll
    for (int i = 0; i < 4; ++i) {
      float4 v = *(const float4*)(colp + i * 4);
      int ig = hi * 16 + i * 4;
      Aw[(ig + 0) * 33 + jj] = v.x;
      Aw[(ig + 1) * 33 + jj] = v.y;
      Aw[(ig + 2) * 33 + jj] = v.z;
      Aw[(ig + 3) * 33 + jj] = v.w;
    }
  }
  WAVE_SYNC();

  float logabs = 0.f;
  int negs = 0;
  for (int k = 0; k < 32; ++k) {
    // isamax over rows k..31 of column k (ties -> first index)
    float v = -1.f;
    int vi = lane;
    if (lane >= k && lane < 32) v = fabsf(Aw[lane * 33 + k]);
    #pragma unroll
    for (int off = 32; off > 0; off >>= 1) {
      float ov = __shfl_xor(v, off);
      int oi = __shfl_xor(vi, off);
      if (ov > v || (ov == v && oi < vi)) { v = ov; vi = oi; }
    }
    int p = vi;                          // uniform across the wave
    if (p != k) {
      negs ^= 1;
      if (lane < 32) {
        float tmp = Aw[k * 33 + lane];
        Aw[k * 33 + lane] = Aw[p * 33 + lane];
        Aw[p * 33 + lane] = tmp;
      }
    }
    WAVE_SYNC();
    float piv = Aw[k * 33 + k];
    if (piv < 0.f) negs ^= 1;
    logabs += logf(fabsf(piv));
    if (lane > k && lane < 32) {
      float l = Aw[lane * 33 + k];
      if (fabsf(piv) >= 1.17549435e-38f) l = l * (1.0f / piv);  // sscal path
      else                               l = l / piv;           // tiny pivot
      Aw[lane * 33 + k] = l;
    }
    WAVE_SYNC();
    {
      const int mid = (k + 33) >> 1;         // balanced split of k+1..31
      const int j   = lane & 31;
      const int ilo = (lane < 32) ? (k + 1) : mid;
      const int ihi = (lane < 32) ? mid : 32;
      if (j > k) {
        float nukj = -Aw[k * 33 + j];
        for (int i = ilo; i < ihi; ++i)
          Aw[i * 33 + j] = fmaf(nukj, Aw[i * 33 + k], Aw[i * 33 + j]);
      }
    }
    WAVE_SYNC();
  }

  if (lane == 0) {
    out[b]       = logabs;                                   // Re: log|det|
    out[B_N + b] = (negs & 1) ? 3.14159265358979f : 0.0f;    // Im: arg(sign)
  }
}

// ---------------------------------------------------------------------------
extern "C" void kernel_launch(void* const* d_in, const int* in_sizes, int n_in,
                              void* d_out, int out_size, void* d_ws, size_t ws_size,
                              hipStream_t stream) {
  const float* n   = (const float*)d_in[0];
  const float* Phi = (const float*)d_in[1];
  const float* W1  = (const float*)d_in[2];
  const float* b1  = (const float*)d_in[3];
  const float* W2  = (const float*)d_in[4];
  const float* b2  = (const float*)d_in[5];
  float* out = (float*)d_out;

  char* ws = (char*)d_ws;
  float*        h_ws       = (float*)ws;                                  // 8 MB
  float*        phi_bucket = (float*)(ws + (size_t)8  * 1024 * 1024);     // 16 MB
  float*        W2t        = (float*)(ws + (size_t)24 * 1024 * 1024);     // 8 MB
  unsigned int* mask       = (unsigned int*)(ws + (size_t)32 * 1024 * 1024); // 64 KB
  int*          bent       = (int*)(ws + (size_t)32 * 1024 * 1024 + 65536);  // 2 MB
  int*          loc        = (int*)(ws + (size_t)34 * 1024 * 1024 + 65536);  // 512 KB
  int*          bcnt       = (int*)(ws + (size_t)34 * 1024 * 1024 + 65536 + 524288);
  int*          boff       = (int*)(ws + (size_t)34 * 1024 * 1024 + 65536 + 524288 + 4096);

  hipLaunchKernelGGL(k_w2t, dim3(H_N), dim3(256), 0, stream, W2, W2t);
  hipLaunchKernelGGL(k1_idx_h, dim3(B_N), dim3(256), 0, stream,
                     n, W1, b1, h_ws, mask);
  hipLaunchKernelGGL(k_fill, dim3(M_N), dim3(256), 0, stream,
                     mask, bcnt, boff, bent, loc);
  hipLaunchKernelGGL(k2_gemm_gather, dim3(M_N, 32), dim3(256), 0, stream,
                     h_ws, W2t, b2, Phi, bcnt, boff, bent, phi_bucket);
  hipLaunchKernelGGL(k3_det, dim3(B_N / 4), dim3(256), 0, stream,
                     phi_bucket, loc, out);
}

// Round 14
// 183.237 us; speedup vs baseline: 1.2905x; 1.2905x over previous
//
#include <hip/hip_runtime.h>
#include <hip/hip_bf16.h>
#include <math.h>

#define B_N 4096
#define M_N 128
#define F_N 32
#define H_N 512
#define NFM 4096   // F*M

// wave-local LDS sync: all lanes of a wave run in lockstep, so a waitcnt on
// outstanding LDS ops makes prior cross-lane LDS writes visible to reads.
#define WAVE_SYNC() do { \
  asm volatile("s_waitcnt lgkmcnt(0)" ::: "memory"); \
  __builtin_amdgcn_sched_barrier(0); \
} while (0)

// ---------------------------------------------------------------------------
// Kernel 1: occupied-index extraction (wave ballot) + hidden layer.
// No atomics: writes the 128-bit occupancy mask per sample; buckets built
// deterministically by k_fill (fused count+fill), sorted by ascending b.
//   h[b,:] = tanhf( sum_j W1[idx_j,:] + b1 )   (ascending-j chain, fp32)
// ---------------------------------------------------------------------------
__global__ __launch_bounds__(256) void k1_idx_h(
    const float* __restrict__ n, const float* __restrict__ W1,
    const float* __restrict__ b1, float* __restrict__ h_ws,
    unsigned int* __restrict__ mask)
{
  __shared__ int s_idx[F_N];
  __shared__ int s_cnt0;
  const int b = blockIdx.x;
  const int t = threadIdx.x;

  bool p = false;
  int before = 0;
  if (t < 128) {
    float v = n[(size_t)b * M_N + t];
    p = v > 0.5f;
    unsigned long long m = __ballot(p);
    int lane = t & 63;
    before = __popcll(m & ((1ull << lane) - 1ull));
    if (lane == 0) {
      if (t < 64) { mask[b*4+0] = (unsigned)m; mask[b*4+1] = (unsigned)(m>>32); }
      else        { mask[b*4+2] = (unsigned)m; mask[b*4+3] = (unsigned)(m>>32); }
    }
    if (t < 64) {
      if (lane == 0) s_cnt0 = __popcll(m);
      if (p) s_idx[before] = t;          // ascending within wave 0
    }
  }
  __syncthreads();
  if (t >= 64 && t < 128 && p) s_idx[s_cnt0 + before] = t;
  __syncthreads();

  #pragma unroll
  for (int cc = 0; cc < 2; ++cc) {
    int c = t + cc * 256;
    float acc = 0.0f;
    #pragma unroll
    for (int j = 0; j < F_N; ++j)
      acc += W1[(size_t)s_idx[j] * H_N + c];
    acc += b1[c];                        // b1 = zeros: exact
    h_ws[(size_t)b * H_N + c] = tanhf(acc);
  }
}

// ---------------------------------------------------------------------------
// k_w2t: pre-transpose W2 into bucket-friendly layout:
//   W2t[c*H_N*F_N + k*F_N + ig] = W2[k*NFM + ig*M_N + c]
// (round 9: killed the 128 MB in-k2 column-gather line amplification)
// ---------------------------------------------------------------------------
__global__ __launch_bounds__(256) void k_w2t(
    const float* __restrict__ W2, float* __restrict__ W2t)
{
  __shared__ float lds[32 * 132];
  const int k = blockIdx.x;
  const int t = threadIdx.x;

  #pragma unroll
  for (int i = 0; i < 4; ++i) {
    int m0 = i * 1024 + t * 4;             // never crosses a 128 boundary
    float4 v = *(const float4*)&W2[(size_t)k * NFM + m0];
    int ig = m0 >> 7, c = m0 & 127;
    lds[ig * 132 + c + 0] = v.x;
    lds[ig * 132 + c + 1] = v.y;
    lds[ig * 132 + c + 2] = v.z;
    lds[ig * 132 + c + 3] = v.w;
  }
  __syncthreads();

  const int c  = t >> 1;
  const int ih = (t & 1) * 16;
  float* outp = W2t + (size_t)c * (H_N * F_N) + k * F_N + ih;
  #pragma unroll
  for (int i = 0; i < 4; ++i) {
    int ig = ih + i * 4;
    float4 v = make_float4(lds[(ig + 0) * 132 + c], lds[(ig + 1) * 132 + c],
                           lds[(ig + 2) * 132 + c], lds[(ig + 3) * 132 + c]);
    *(float4*)(outp + i * 4) = v;
  }
}

// ---------------------------------------------------------------------------
// k_fill (fused count+fill):
// Pass 1: block c computes cnt_c AND boff_c = sum_b rank_b(c) directly.
// Pass 2: deterministic fill, entries sorted by ascending sample b:
//   bent[c*B_N + pos] = (b<<5) | j ;  loc[b*32 + j] = boff_c + pos
// ---------------------------------------------------------------------------
__global__ __launch_bounds__(256) void k_fill(
    const unsigned int* __restrict__ mask,
    int* __restrict__ bcnt, int* __restrict__ boff,
    int* __restrict__ bent, int* __restrict__ loc)
{
  const int c = blockIdx.x;
  const int t = threadIdx.x;
  const int w = t >> 6, lane = t & 63;
  const int word = c >> 5, bit = c & 31;
  __shared__ int s_wcnt[4];
  __shared__ int s_red[8];
  __shared__ int s_run;

  // ---- pass 1: count + offset ----
  int cnt_loc = 0, off_loc = 0;
  for (int b = t; b < B_N; b += 256) {
    unsigned m0 = mask[(size_t)b*4+0], m1 = mask[(size_t)b*4+1];
    unsigned m2 = mask[(size_t)b*4+2], m3 = mask[(size_t)b*4+3];
    unsigned wv = (word == 0) ? m0 : (word == 1) ? m1 : (word == 2) ? m2 : m3;
    cnt_loc += (int)((wv >> bit) & 1u);
    int r = __popc(wv & ((1u << bit) - 1u));
    if (word > 0) r += __popc(m0);
    if (word > 1) r += __popc(m1);
    if (word > 2) r += __popc(m2);
    off_loc += r;
  }
  #pragma unroll
  for (int off = 32; off > 0; off >>= 1) {
    cnt_loc += __shfl_down(cnt_loc, off);
    off_loc += __shfl_down(off_loc, off);
  }
  if (lane == 0) { s_red[w] = cnt_loc; s_red[4 + w] = off_loc; }
  __syncthreads();
  const int cnt_tot = s_red[0] + s_red[1] + s_red[2] + s_red[3];
  const int off_tot = s_red[4] + s_red[5] + s_red[6] + s_red[7];
  if (t == 0) { bcnt[c] = cnt_tot; boff[c] = off_tot; s_run = 0; }
  __syncthreads();

  // ---- pass 2: fill (ascending b) ----
  for (int chunk = 0; chunk < B_N; chunk += 256) {
    const int b = chunk + t;
    unsigned m0 = mask[(size_t)b*4+0], m1 = mask[(size_t)b*4+1];
    unsigned m2 = mask[(size_t)b*4+2], m3 = mask[(size_t)b*4+3];
    unsigned wv = (word == 0) ? m0 : (word == 1) ? m1 : (word == 2) ? m2 : m3;
    bool p = (wv >> bit) & 1u;
    int j = __popc(wv & ((1u << bit) - 1u));
    if (word > 0) j += __popc(m0);
    if (word > 1) j += __popc(m1);
    if (word > 2) j += __popc(m2);

    unsigned long long bal = __ballot(p);
    int before = __popcll(bal & ((1ull << lane) - 1ull));
    if (lane == 0) s_wcnt[w] = __popcll(bal);
    __syncthreads();
    int wbase = s_run;
    for (int i = 0; i < w; ++i) wbase += s_wcnt[i];
    if (p) {
      int pos = wbase + before;              // bucket-local, ascending b
      bent[(size_t)c * B_N + pos] = (b << 5) | j;
      loc[b * 32 + j] = off_tot + pos;
    }
    __syncthreads();
    if (t == 0) s_run += s_wcnt[0] + s_wcnt[1] + s_wcnt[2] + s_wcnt[3];
    __syncthreads();
  }
}

// ---------------------------------------------------------------------------
// Kernel 2 (ROUND 25 = ROUND 9's staged k2 VERBATIM, the measured optimum).
// Family post-mortem: staged r9 = 99 us (37.6% VALUBusy); staged variants
//   r11/r12 = 108/119; SGPR-direct r3 = 877; VGPR-direct r13 = 164
//   (VMEM latency per quad uncovered at 1-quad prefetch; addressing VALU
//   grew). All alternatives exhausted -> pre-committed revert to r9.
// Per bucket c: [cnt_c x 512] @ [512 x 32], B panel contiguous from W2t
// (L2-resident). 4x4 micro-tile, BK=16, double-buffered LDS, one barrier
// per k-tile, b-sorted entries, bucket-major phi writes.
// ARITHMETIC BIT-IDENTICAL: each output = one ascending-k fmaf chain
// (t ascending, kk ascending, single accumulator); epilogue Phi+(acc+b2).
// absmax must stay exactly 0.203125.
// ---------------------------------------------------------------------------
__global__ __launch_bounds__(256) void k2_gemm_gather(
    const float* __restrict__ h, const float* __restrict__ W2t,
    const float* __restrict__ b2, const float* __restrict__ Phi,
    const int* __restrict__ bcnt, const int* __restrict__ boff,
    const int* __restrict__ bent, float* __restrict__ phi_bucket)
{
  // per buffer: At [16][132] = 2112 floats + Bt [16][32] = 512 -> 2624
  __shared__ __align__(16) float smem[2 * 2624];   // 20992 B
  __shared__ int s_b[128];

  const int tid = threadIdx.x;               // 0..255
  const int c   = blockIdx.x;                // orbital 0..127
  const int cnt = bcnt[c];
  const int t0  = blockIdx.y * 128;          // row-tile base within bucket
  if (t0 >= cnt) return;                     // block-uniform early exit
  const int base = boff[c];
  const float* w2tc = W2t + (size_t)c * (H_N * F_N);

  if (tid < 128) {
    int ii = t0 + tid;
    int e  = bent[(size_t)c * B_N + (ii < cnt ? ii : cnt - 1)];  // cnt >= 1
    s_b[tid] = e >> 5;
  }
  __syncthreads();

  const int kA  = tid & 15;                  // A stage: kk (0..15)
  const int rbA = (tid >> 4) * 8;            // A stage: row base (0..120)
  const int tx  = tid & 7;                   // col group: igs tx*4..+3
  const int tyr = tid >> 3;                  // row group 0..31: rows tyr*4..+3

  int rowb[8];
  #pragma unroll
  for (int i = 0; i < 8; ++i) rowb[i] = s_b[rbA + i];

  float acc[4][4];
  #pragma unroll
  for (int i = 0; i < 4; ++i)
    #pragma unroll
    for (int u = 0; u < 4; ++u) acc[i][u] = 0.f;

  float aReg[8], bReg0, bReg1;

  // ---- prologue: stage k-tile 0 into buf0 ----
  #pragma unroll
  for (int i = 0; i < 8; ++i)
    aReg[i] = h[(size_t)rowb[i] * H_N + kA];
  bReg0 = w2tc[tid];                         // rows 0..7  of Bt (linear)
  bReg1 = w2tc[256 + tid];                   // rows 8..15 of Bt
  *(float4*)&smem[kA * 132 + rbA] =
      make_float4(aReg[0], aReg[1], aReg[2], aReg[3]);
  *(float4*)&smem[kA * 132 + rbA + 4] =
      make_float4(aReg[4], aReg[5], aReg[6], aReg[7]);
  smem[2112 + tid] = bReg0;
  smem[2112 + 256 + tid] = bReg1;
  __syncthreads();

  #pragma unroll 1
  for (int t = 0; t < 32; ++t) {
    float* Atc = smem + (t & 1) * 2624;
    float* Btc = Atc + 2112;
    float* Atn = smem + ((t + 1) & 1) * 2624;
    float* Btn = Atn + 2112;

    // issue next tile's global loads (latency hides under compute)
    if (t < 31) {
      int k0n = (t + 1) * 16;
      #pragma unroll
      for (int i = 0; i < 8; ++i)
        aReg[i] = h[(size_t)rowb[i] * H_N + k0n + kA];
      bReg0 = w2tc[k0n * 32 + tid];
      bReg1 = w2tc[k0n * 32 + 256 + tid];
    }

    // compute tile t: 2 x ds_read_b128 + 16 fmaf per kk
    #pragma unroll
    for (int kk = 0; kk < 16; ++kk) {
      float4 av = *(const float4*)&Atc[kk * 132 + tyr * 4];
      float4 bv = *(const float4*)&Btc[kk * 32 + tx * 4];
      float a4[4] = {av.x, av.y, av.z, av.w};
      float b4[4] = {bv.x, bv.y, bv.z, bv.w};
      #pragma unroll
      for (int i = 0; i < 4; ++i)
        #pragma unroll
        for (int u = 0; u < 4; ++u)
          acc[i][u] = fmaf(a4[i], b4[u], acc[i][u]);
    }

    // stage tile t+1 into the idle buffer; single barrier flips
    if (t < 31) {
      *(float4*)&Atn[kA * 132 + rbA] =
          make_float4(aReg[0], aReg[1], aReg[2], aReg[3]);
      *(float4*)&Atn[kA * 132 + rbA + 4] =
          make_float4(aReg[4], aReg[5], aReg[6], aReg[7]);
      Btn[tid] = bReg0;
      Btn[256 + tid] = bReg1;
      __syncthreads();
    }
  }

  // ---- epilogue: coalesced float4 writes into bucket-major phi ----
  #pragma unroll
  for (int i = 0; i < 4; ++i) {
    int r = tyr * 4 + i;
    if (t0 + r < cnt) {
      int col = base + t0 + r;               // global column index
      float v[4];
      #pragma unroll
      for (int u = 0; u < 4; ++u) {
        int ig   = tx * 4 + u;
        int colw = ig * M_N + c;
        v[u] = Phi[colw] + (acc[i][u] + b2[colw]);
      }
      *(float4*)&phi_bucket[(size_t)col * 32 + tx * 4] =
          make_float4(v[0], v[1], v[2], v[3]);
    }
  }
}

// ---------------------------------------------------------------------------
// Kernel 3: batched 32x32 fp32 LU replicating LAPACK sgetf2 exactly.
// Rank-1 update uses BOTH 32-lane halves (rows split [k+1,mid)/[mid,32);
// elements within an iteration are independent -> bit-identical).
// Loads columns from bucket-major phi_bucket via loc (contiguous 128 B).
// PLANAR complex output: out[0..B-1] = log|det|, out[B..2B-1] = arg(sign)
// ---------------------------------------------------------------------------
__global__ __launch_bounds__(256) void k3_det(
    const float* __restrict__ phi_bucket, const int* __restrict__ loc,
    float* __restrict__ out)
{
  __shared__ float A[4][32 * 33];
  const int w = threadIdx.x >> 6;
  const int lane = threadIdx.x & 63;
  const int b = blockIdx.x * 4 + w;
  float* Aw = A[w];

  {
    const int jj = lane & 31;
    const int hi = lane >> 5;              // 0 or 1: ig halves
    int lcol = loc[b * 32 + jj];
    const float* colp = phi_bucket + (size_t)lcol * 32 + hi * 16;
    #pragma unroll
    for (int i = 0; i < 4; ++i) {
      float4 v = *(const float4*)(colp + i * 4);
      int ig = hi * 16 + i * 4;
      Aw[(ig + 0) * 33 + jj] = v.x;
      Aw[(ig + 1) * 33 + jj] = v.y;
      Aw[(ig + 2) * 33 + jj] = v.z;
      Aw[(ig + 3) * 33 + jj] = v.w;
    }
  }
  WAVE_SYNC();

  float logabs = 0.f;
  int negs = 0;
  for (int k = 0; k < 32; ++k) {
    // isamax over rows k..31 of column k (ties -> first index)
    float v = -1.f;
    int vi = lane;
    if (lane >= k && lane < 32) v = fabsf(Aw[lane * 33 + k]);
    #pragma unroll
    for (int off = 32; off > 0; off >>= 1) {
      float ov = __shfl_xor(v, off);
      int oi = __shfl_xor(vi, off);
      if (ov > v || (ov == v && oi < vi)) { v = ov; vi = oi; }
    }
    int p = vi;                          // uniform across the wave
    if (p != k) {
      negs ^= 1;
      if (lane < 32) {
        float tmp = Aw[k * 33 + lane];
        Aw[k * 33 + lane] = Aw[p * 33 + lane];
        Aw[p * 33 + lane] = tmp;
      }
    }
    WAVE_SYNC();
    float piv = Aw[k * 33 + k];
    if (piv < 0.f) negs ^= 1;
    logabs += logf(fabsf(piv));
    if (lane > k && lane < 32) {
      float l = Aw[lane * 33 + k];
      if (fabsf(piv) >= 1.17549435e-38f) l = l * (1.0f / piv);  // sscal path
      else                               l = l / piv;           // tiny pivot
      Aw[lane * 33 + k] = l;
    }
    WAVE_SYNC();
    {
      const int mid = (k + 33) >> 1;         // balanced split of k+1..31
      const int j   = lane & 31;
      const int ilo = (lane < 32) ? (k + 1) : mid;
      const int ihi = (lane < 32) ? mid : 32;
      if (j > k) {
        float nukj = -Aw[k * 33 + j];
        for (int i = ilo; i < ihi; ++i)
          Aw[i * 33 + j] = fmaf(nukj, Aw[i * 33 + k], Aw[i * 33 + j]);
      }
    }
    WAVE_SYNC();
  }

  if (lane == 0) {
    out[b]       = logabs;                                   // Re: log|det|
    out[B_N + b] = (negs & 1) ? 3.14159265358979f : 0.0f;    // Im: arg(sign)
  }
}

// ---------------------------------------------------------------------------
extern "C" void kernel_launch(void* const* d_in, const int* in_sizes, int n_in,
                              void* d_out, int out_size, void* d_ws, size_t ws_size,
                              hipStream_t stream) {
  const float* n   = (const float*)d_in[0];
  const float* Phi = (const float*)d_in[1];
  const float* W1  = (const float*)d_in[2];
  const float* b1  = (const float*)d_in[3];
  const float* W2  = (const float*)d_in[4];
  const float* b2  = (const float*)d_in[5];
  float* out = (float*)d_out;

  char* ws = (char*)d_ws;
  float*        h_ws       = (float*)ws;                                  // 8 MB
  float*        phi_bucket = (float*)(ws + (size_t)8  * 1024 * 1024);     // 16 MB
  float*        W2t        = (float*)(ws + (size_t)24 * 1024 * 1024);     // 8 MB
  unsigned int* mask       = (unsigned int*)(ws + (size_t)32 * 1024 * 1024); // 64 KB
  int*          bent       = (int*)(ws + (size_t)32 * 1024 * 1024 + 65536);  // 2 MB
  int*          loc        = (int*)(ws + (size_t)34 * 1024 * 1024 + 65536);  // 512 KB
  int*          bcnt       = (int*)(ws + (size_t)34 * 1024 * 1024 + 65536 + 524288);
  int*          boff       = (int*)(ws + (size_t)34 * 1024 * 1024 + 65536 + 524288 + 4096);

  hipLaunchKernelGGL(k_w2t, dim3(H_N), dim3(256), 0, stream, W2, W2t);
  hipLaunchKernelGGL(k1_idx_h, dim3(B_N), dim3(256), 0, stream,
                     n, W1, b1, h_ws, mask);
  hipLaunchKernelGGL(k_fill, dim3(M_N), dim3(256), 0, stream,
                     mask, bcnt, boff, bent, loc);
  hipLaunchKernelGGL(k2_gemm_gather, dim3(M_N, 32), dim3(256), 0, stream,
                     h_ws, W2t, b2, Phi, bcnt, boff, bent, phi_bucket);
  hipLaunchKernelGGL(k3_det, dim3(B_N / 4), dim3(256), 0, stream,
                     phi_bucket, loc, out);
}

// Round 15
// 179.477 us; speedup vs baseline: 1.3175x; 1.0209x over previous
//
#include <hip/hip_runtime.h>
#include <hip/hip_bf16.h>
#include <math.h>

#define B_N 4096
#define M_N 128
#define F_N 32
#define H_N 512
#define NFM 4096   // F*M

// wave-local LDS sync: all lanes of a wave run in lockstep, so a waitcnt on
// outstanding LDS ops makes prior cross-lane LDS writes visible to reads.
#define WAVE_SYNC() do { \
  asm volatile("s_waitcnt lgkmcnt(0)" ::: "memory"); \
  __builtin_amdgcn_sched_barrier(0); \
} while (0)

// ---------------------------------------------------------------------------
// k_pre (ROUND 26): FUSED k_w2t + k1 — independent work, one launch.
//   blocks 0..511   : W2 transpose (k = blockIdx.x), dispatched first so its
//                     16 MB of L2 traffic overlaps k1 compute.
//   blocks 512..2559: k1, TWO samples per block (b = 2*(blk-512) + (t>>7)),
//                     4 cols/thread via float4 W1 loads (1024 B per wave,
//                     perfectly coalesced; 4x fewer load instructions than
//                     the scalar version, same bytes).
// k1 arithmetic BIT-IDENTICAL: per column c, acc = ((0 + W1[idx_0][c]) +
// W1[idx_1][c]) + ... ascending j, then + b1[c], then tanhf — the float4 is
// just 4 independent scalar chains. Mask words identical.
// ---------------------------------------------------------------------------
__global__ __launch_bounds__(256) void k_pre(
    const float* __restrict__ n, const float* __restrict__ W1,
    const float* __restrict__ b1, const float* __restrict__ W2,
    float* __restrict__ W2t, float* __restrict__ h_ws,
    unsigned int* __restrict__ mask)
{
  __shared__ float s_buf[32 * 132];          // w2t transpose tile
  __shared__ int s_idx[2][F_N];
  __shared__ int s_cnt0[2];

  const int t = threadIdx.x;

  if (blockIdx.x < 512) {
    // ---- W2 transpose: W2t[c][k][ig] = W2[k][ig*128+c] ----
    const int k = blockIdx.x;
    #pragma unroll
    for (int i = 0; i < 4; ++i) {
      int m0 = i * 1024 + t * 4;             // never crosses a 128 boundary
      float4 v = *(const float4*)&W2[(size_t)k * NFM + m0];
      int ig = m0 >> 7, c = m0 & 127;
      s_buf[ig * 132 + c + 0] = v.x;
      s_buf[ig * 132 + c + 1] = v.y;
      s_buf[ig * 132 + c + 2] = v.z;
      s_buf[ig * 132 + c + 3] = v.w;
    }
    __syncthreads();
    const int c  = t >> 1;
    const int ih = (t & 1) * 16;
    float* outp = W2t + (size_t)c * (H_N * F_N) + k * F_N + ih;
    #pragma unroll
    for (int i = 0; i < 4; ++i) {
      int ig = ih + i * 4;
      float4 v = make_float4(s_buf[(ig+0)*132 + c], s_buf[(ig+1)*132 + c],
                             s_buf[(ig+2)*132 + c], s_buf[(ig+3)*132 + c]);
      *(float4*)(outp + i * 4) = v;
    }
    return;
  }

  // ---- k1: two samples per block ----
  const int half = t >> 7;                   // 0: sample A, 1: sample B
  const int tl   = t & 127;                  // orbital / col-group index
  const int b    = (blockIdx.x - 512) * 2 + half;
  const int lane = t & 63;

  {
    float v = n[(size_t)b * M_N + tl];
    bool p = v > 0.5f;
    unsigned long long m = __ballot(p);      // wave = one 64-orbital half
    int before = __popcll(m & ((1ull << lane) - 1ull));
    if (lane == 0) {
      int w2 = (tl < 64) ? 0 : 2;
      mask[b*4 + w2 + 0] = (unsigned)m;
      mask[b*4 + w2 + 1] = (unsigned)(m >> 32);
    }
    if (tl < 64) {
      if (lane == 0) s_cnt0[half] = __popcll(m);
      if (p) s_idx[half][before] = tl;       // ascending within low half
    }
    __syncthreads();
    if (tl >= 64 && p) s_idx[half][s_cnt0[half] + before] = tl;
    __syncthreads();
  }

  const int c0 = tl * 4;                     // 4 consecutive cols
  float4 acc = make_float4(0.f, 0.f, 0.f, 0.f);
  #pragma unroll
  for (int j = 0; j < F_N; ++j) {
    float4 wv = *(const float4*)&W1[(size_t)s_idx[half][j] * H_N + c0];
    acc.x += wv.x; acc.y += wv.y; acc.z += wv.z; acc.w += wv.w;
  }
  float4 bv = *(const float4*)&b1[c0];       // b1 = zeros: exact
  acc.x = tanhf(acc.x + bv.x);
  acc.y = tanhf(acc.y + bv.y);
  acc.z = tanhf(acc.z + bv.z);
  acc.w = tanhf(acc.w + bv.w);
  *(float4*)&h_ws[(size_t)b * H_N + c0] = acc;
}

// ---------------------------------------------------------------------------
// k_fill (ROUND 26: barrier-diet — 48 barriers -> 2):
// Pass 1: per-(chunk,wave) ballot counts -> s_wcnt[64]; wave-reduced totals
//   give cnt_c and boff_c = sum_b rank_b(c). Thread 0 exclusive-prefixes
//   s_wcnt into s_pre. Pass 2: zero barriers — each write position is
//   s_pre[ch*4+w] + lane rank, identical VALUES to the old serial-s_run
//   version (chunk-prefix + wave-prefix + before). Entries ascending b.
//   bent[c*B_N + pos] = (b<<5) | j ;  loc[b*32 + j] = boff_c + pos
// ---------------------------------------------------------------------------
__global__ __launch_bounds__(256) void k_fill(
    const unsigned int* __restrict__ mask,
    int* __restrict__ bcnt, int* __restrict__ boff,
    int* __restrict__ bent, int* __restrict__ loc)
{
  const int c = blockIdx.x;
  const int t = threadIdx.x;
  const int w = t >> 6, lane = t & 63;
  const int word = c >> 5, bit = c & 31;
  __shared__ int s_wcnt[64];                 // 16 chunks x 4 waves
  __shared__ int s_pre[64];
  __shared__ int s_red[8];

  // ---- pass 1: counts ----
  int cnt_loc = 0, off_loc = 0;
  #pragma unroll 1
  for (int ch = 0; ch < 16; ++ch) {
    const int b = ch * 256 + t;
    unsigned m0 = mask[(size_t)b*4+0], m1 = mask[(size_t)b*4+1];
    unsigned m2 = mask[(size_t)b*4+2], m3 = mask[(size_t)b*4+3];
    unsigned wv = (word == 0) ? m0 : (word == 1) ? m1 : (word == 2) ? m2 : m3;
    bool p = (wv >> bit) & 1u;
    int r = __popc(wv & ((1u << bit) - 1u));
    if (word > 0) r += __popc(m0);
    if (word > 1) r += __popc(m1);
    if (word > 2) r += __popc(m2);
    unsigned long long bal = __ballot(p);
    if (lane == 0) s_wcnt[ch * 4 + w] = __popcll(bal);
    cnt_loc += (int)p;
    off_loc += r;
  }
  #pragma unroll
  for (int off = 32; off > 0; off >>= 1) {
    cnt_loc += __shfl_down(cnt_loc, off);
    off_loc += __shfl_down(off_loc, off);
  }
  if (lane == 0) { s_red[w] = cnt_loc; s_red[4 + w] = off_loc; }
  __syncthreads();                           // barrier 1
  const int cnt_tot = s_red[0] + s_red[1] + s_red[2] + s_red[3];
  const int off_tot = s_red[4] + s_red[5] + s_red[6] + s_red[7];
  if (t == 0) {
    bcnt[c] = cnt_tot; boff[c] = off_tot;
    int run = 0;
    #pragma unroll
    for (int i = 0; i < 64; ++i) { s_pre[i] = run; run += s_wcnt[i]; }
  }
  __syncthreads();                           // barrier 2

  // ---- pass 2: fill (ascending b), no barriers ----
  #pragma unroll 1
  for (int ch = 0; ch < 16; ++ch) {
    const int b = ch * 256 + t;
    unsigned m0 = mask[(size_t)b*4+0], m1 = mask[(size_t)b*4+1];
    unsigned m2 = mask[(size_t)b*4+2], m3 = mask[(size_t)b*4+3];
    unsigned wv = (word == 0) ? m0 : (word == 1) ? m1 : (word == 2) ? m2 : m3;
    bool p = (wv >> bit) & 1u;
    int j = __popc(wv & ((1u << bit) - 1u));
    if (word > 0) j += __popc(m0);
    if (word > 1) j += __popc(m1);
    if (word > 2) j += __popc(m2);
    unsigned long long bal = __ballot(p);
    int before = __popcll(bal & ((1ull << lane) - 1ull));
    if (p) {
      int pos = s_pre[ch * 4 + w] + before;  // bucket-local, ascending b
      bent[(size_t)c * B_N + pos] = (b << 5) | j;
      loc[b * 32 + j] = off_tot + pos;
    }
  }
}

// ---------------------------------------------------------------------------
// Kernel 2 (round 9's staged k2 VERBATIM — the measured family optimum).
// Per bucket c: [cnt_c x 512] @ [512 x 32], B panel contiguous from W2t
// (L2-resident). 4x4 micro-tile, BK=16, double-buffered LDS, one barrier
// per k-tile, b-sorted entries, bucket-major phi writes.
// ARITHMETIC BIT-IDENTICAL: each output = one ascending-k fmaf chain
// (t ascending, kk ascending, single accumulator); epilogue Phi+(acc+b2).
// absmax must stay exactly 0.203125.
// ---------------------------------------------------------------------------
__global__ __launch_bounds__(256) void k2_gemm_gather(
    const float* __restrict__ h, const float* __restrict__ W2t,
    const float* __restrict__ b2, const float* __restrict__ Phi,
    const int* __restrict__ bcnt, const int* __restrict__ boff,
    const int* __restrict__ bent, float* __restrict__ phi_bucket)
{
  // per buffer: At [16][132] = 2112 floats + Bt [16][32] = 512 -> 2624
  __shared__ __align__(16) float smem[2 * 2624];   // 20992 B
  __shared__ int s_b[128];

  const int tid = threadIdx.x;               // 0..255
  const int c   = blockIdx.x;                // orbital 0..127
  const int cnt = bcnt[c];
  const int t0  = blockIdx.y * 128;          // row-tile base within bucket
  if (t0 >= cnt) return;                     // block-uniform early exit
  const int base = boff[c];
  const float* w2tc = W2t + (size_t)c * (H_N * F_N);

  if (tid < 128) {
    int ii = t0 + tid;
    int e  = bent[(size_t)c * B_N + (ii < cnt ? ii : cnt - 1)];  // cnt >= 1
    s_b[tid] = e >> 5;
  }
  __syncthreads();

  const int kA  = tid & 15;                  // A stage: kk (0..15)
  const int rbA = (tid >> 4) * 8;            // A stage: row base (0..120)
  const int tx  = tid & 7;                   // col group: igs tx*4..+3
  const int tyr = tid >> 3;                  // row group 0..31: rows tyr*4..+3

  int rowb[8];
  #pragma unroll
  for (int i = 0; i < 8; ++i) rowb[i] = s_b[rbA + i];

  float acc[4][4];
  #pragma unroll
  for (int i = 0; i < 4; ++i)
    #pragma unroll
    for (int u = 0; u < 4; ++u) acc[i][u] = 0.f;

  float aReg[8], bReg0, bReg1;

  // ---- prologue: stage k-tile 0 into buf0 ----
  #pragma unroll
  for (int i = 0; i < 8; ++i)
    aReg[i] = h[(size_t)rowb[i] * H_N + kA];
  bReg0 = w2tc[tid];                         // rows 0..7  of Bt (linear)
  bReg1 = w2tc[256 + tid];                   // rows 8..15 of Bt
  *(float4*)&smem[kA * 132 + rbA] =
      make_float4(aReg[0], aReg[1], aReg[2], aReg[3]);
  *(float4*)&smem[kA * 132 + rbA + 4] =
      make_float4(aReg[4], aReg[5], aReg[6], aReg[7]);
  smem[2112 + tid] = bReg0;
  smem[2112 + 256 + tid] = bReg1;
  __syncthreads();

  #pragma unroll 1
  for (int t = 0; t < 32; ++t) {
    float* Atc = smem + (t & 1) * 2624;
    float* Btc = Atc + 2112;
    float* Atn = smem + ((t + 1) & 1) * 2624;
    float* Btn = Atn + 2112;

    // issue next tile's global loads (latency hides under compute)
    if (t < 31) {
      int k0n = (t + 1) * 16;
      #pragma unroll
      for (int i = 0; i < 8; ++i)
        aReg[i] = h[(size_t)rowb[i] * H_N + k0n + kA];
      bReg0 = w2tc[k0n * 32 + tid];
      bReg1 = w2tc[k0n * 32 + 256 + tid];
    }

    // compute tile t: 2 x ds_read_b128 + 16 fmaf per kk
    #pragma unroll
    for (int kk = 0; kk < 16; ++kk) {
      float4 av = *(const float4*)&Atc[kk * 132 + tyr * 4];
      float4 bv = *(const float4*)&Btc[kk * 32 + tx * 4];
      float a4[4] = {av.x, av.y, av.z, av.w};
      float b4[4] = {bv.x, bv.y, bv.z, bv.w};
      #pragma unroll
      for (int i = 0; i < 4; ++i)
        #pragma unroll
        for (int u = 0; u < 4; ++u)
          acc[i][u] = fmaf(a4[i], b4[u], acc[i][u]);
    }

    // stage tile t+1 into the idle buffer; single barrier flips
    if (t < 31) {
      *(float4*)&smem[((t + 1) & 1) * 2624 + kA * 132 + rbA] =
          make_float4(aReg[0], aReg[1], aReg[2], aReg[3]);
      *(float4*)&Atn[kA * 132 + rbA + 4] =
          make_float4(aReg[4], aReg[5], aReg[6], aReg[7]);
      Btn[tid] = bReg0;
      Btn[256 + tid] = bReg1;
      __syncthreads();
    }
  }

  // ---- epilogue: coalesced float4 writes into bucket-major phi ----
  #pragma unroll
  for (int i = 0; i < 4; ++i) {
    int r = tyr * 4 + i;
    if (t0 + r < cnt) {
      int col = base + t0 + r;               // global column index
      float v[4];
      #pragma unroll
      for (int u = 0; u < 4; ++u) {
        int ig   = tx * 4 + u;
        int colw = ig * M_N + c;
        v[u] = Phi[colw] + (acc[i][u] + b2[colw]);
      }
      *(float4*)&phi_bucket[(size_t)col * 32 + tx * 4] =
          make_float4(v[0], v[1], v[2], v[3]);
    }
  }
}

// ---------------------------------------------------------------------------
// Kernel 3: batched 32x32 fp32 LU replicating LAPACK sgetf2 exactly.
// Rank-1 update uses BOTH 32-lane halves (rows split [k+1,mid)/[mid,32);
// elements within an iteration are independent -> bit-identical).
// Loads columns from bucket-major phi_bucket via loc (contiguous 128 B).
// PLANAR complex output: out[0..B-1] = log|det|, out[B..2B-1] = arg(sign)
// ---------------------------------------------------------------------------
__global__ __launch_bounds__(256) void k3_det(
    const float* __restrict__ phi_bucket, const int* __restrict__ loc,
    float* __restrict__ out)
{
  __shared__ float A[4][32 * 33];
  const int w = threadIdx.x >> 6;
  const int lane = threadIdx.x & 63;
  const int b = blockIdx.x * 4 + w;
  float* Aw = A[w];

  {
    const int jj = lane & 31;
    const int hi = lane >> 5;              // 0 or 1: ig halves
    int lcol = loc[b * 32 + jj];
    const float* colp = phi_bucket + (size_t)lcol * 32 + hi * 16;
    #pragma unroll
    for (int i = 0; i < 4; ++i) {
      float4 v = *(const float4*)(colp + i * 4);
      int ig = hi * 16 + i * 4;
      Aw[(ig + 0) * 33 + jj] = v.x;
      Aw[(ig + 1) * 33 + jj] = v.y;
      Aw[(ig + 2) * 33 + jj] = v.z;
      Aw[(ig + 3) * 33 + jj] = v.w;
    }
  }
  WAVE_SYNC();

  float logabs = 0.f;
  int negs = 0;
  for (int k = 0; k < 32; ++k) {
    // isamax over rows k..31 of column k (ties -> first index)
    float v = -1.f;
    int vi = lane;
    if (lane >= k && lane < 32) v = fabsf(Aw[lane * 33 + k]);
    #pragma unroll
    for (int off = 32; off > 0; off >>= 1) {
      float ov = __shfl_xor(v, off);
      int oi = __shfl_xor(vi, off);
      if (ov > v || (ov == v && oi < vi)) { v = ov; vi = oi; }
    }
    int p = vi;                          // uniform across the wave
    if (p != k) {
      negs ^= 1;
      if (lane < 32) {
        float tmp = Aw[k * 33 + lane];
        Aw[k * 33 + lane] = Aw[p * 33 + lane];
        Aw[p * 33 + lane] = tmp;
      }
    }
    WAVE_SYNC();
    float piv = Aw[k * 33 + k];
    if (piv < 0.f) negs ^= 1;
    logabs += logf(fabsf(piv));
    if (lane > k && lane < 32) {
      float l = Aw[lane * 33 + k];
      if (fabsf(piv) >= 1.17549435e-38f) l = l * (1.0f / piv);  // sscal path
      else                               l = l / piv;           // tiny pivot
      Aw[lane * 33 + k] = l;
    }
    WAVE_SYNC();
    {
      const int mid = (k + 33) >> 1;         // balanced split of k+1..31
      const int j   = lane & 31;
      const int ilo = (lane < 32) ? (k + 1) : mid;
      const int ihi = (lane < 32) ? mid : 32;
      if (j > k) {
        float nukj = -Aw[k * 33 + j];
        for (int i = ilo; i < ihi; ++i)
          Aw[i * 33 + j] = fmaf(nukj, Aw[i * 33 + k], Aw[i * 33 + j]);
      }
    }
    WAVE_SYNC();
  }

  if (lane == 0) {
    out[b]       = logabs;                                   // Re: log|det|
    out[B_N + b] = (negs & 1) ? 3.14159265358979f : 0.0f;    // Im: arg(sign)
  }
}

// ---------------------------------------------------------------------------
extern "C" void kernel_launch(void* const* d_in, const int* in_sizes, int n_in,
                              void* d_out, int out_size, void* d_ws, size_t ws_size,
                              hipStream_t stream) {
  const float* n   = (const float*)d_in[0];
  const float* Phi = (const float*)d_in[1];
  const float* W1  = (const float*)d_in[2];
  const float* b1  = (const float*)d_in[3];
  const float* W2  = (const float*)d_in[4];
  const float* b2  = (const float*)d_in[5];
  float* out = (float*)d_out;

  char* ws = (char*)d_ws;
  float*        h_ws       = (float*)ws;                                  // 8 MB
  float*        phi_bucket = (float*)(ws + (size_t)8  * 1024 * 1024);     // 16 MB
  float*        W2t        = (float*)(ws + (size_t)24 * 1024 * 1024);     // 8 MB
  unsigned int* mask       = (unsigned int*)(ws + (size_t)32 * 1024 * 1024); // 64 KB
  int*          bent       = (int*)(ws + (size_t)32 * 1024 * 1024 + 65536);  // 2 MB
  int*          loc        = (int*)(ws + (size_t)34 * 1024 * 1024 + 65536);  // 512 KB
  int*          bcnt       = (int*)(ws + (size_t)34 * 1024 * 1024 + 65536 + 524288);
  int*          boff       = (int*)(ws + (size_t)34 * 1024 * 1024 + 65536 + 524288 + 4096);

  hipLaunchKernelGGL(k_pre, dim3(512 + B_N / 2), dim3(256), 0, stream,
                     n, W1, b1, W2, W2t, h_ws, mask);
  hipLaunchKernelGGL(k_fill, dim3(M_N), dim3(256), 0, stream,
                     mask, bcnt, boff, bent, loc);
  hipLaunchKernelGGL(k2_gemm_gather, dim3(M_N, 32), dim3(256), 0, stream,
                     h_ws, W2t, b2, Phi, bcnt, boff, bent, phi_bucket);
  hipLaunchKernelGGL(k3_det, dim3(B_N / 4), dim3(256), 0, stream,
                     phi_bucket, loc, out);
}